// Round 2
// baseline (3237.449 us; speedup 1.0000x reference)
//
#include <hip/hip_runtime.h>
#include <hip/hip_bf16.h>
#include <cstdint>

// Problem constants
#define B_   64
#define T_   2048
#define CIN  44
#define D_   512
#define DCC  640
#define REDD 160
#define BT   131072        // B_*T_
#define EPSV 1e-5f

typedef __attribute__((ext_vector_type(8))) short short8;
typedef __attribute__((ext_vector_type(4))) float f32x4;

#define MFMA16(a,b,c) __builtin_amdgcn_mfma_f32_16x16x32_bf16(a,b,c,0,0,0)

__device__ __forceinline__ float bf2f(unsigned short u) {
    union { unsigned int i; float f; } v; v.i = ((unsigned int)u) << 16; return v.f;
}
__device__ __forceinline__ unsigned short f2bf(float f) {
    union { float f; unsigned int i; } v; v.f = f;
    unsigned int r = v.i + 0x7FFFu + ((v.i >> 16) & 1u);   // RNE
    return (unsigned short)(r >> 16);
}

// ---------------------------------------------------------------- prep: weights -> bf16 transposed [n][k]
__global__ void kprep(const float* __restrict__ hw2, const float* __restrict__ lw2, const float* __restrict__ ew2,
                      const float* __restrict__ hb2, const float* __restrict__ lb2, const float* __restrict__ eb2,
                      const float* __restrict__ gw,  const float* __restrict__ pw,  const float* __restrict__ ow,
                      unsigned short* __restrict__ w2T, float* __restrict__ b2,
                      unsigned short* __restrict__ gwT, unsigned short* __restrict__ pwT,
                      unsigned short* __restrict__ owT)
{
    int tid = blockIdx.x * blockDim.x + threadIdx.x;
    int nth = gridDim.x * blockDim.x;
    for (int i = tid; i < 640 * 256; i += nth) {           // w2T[n*256 + k_local]
        int n = i >> 8, k = i & 255;
        float v;
        if (n < 256)      v = hw2[k * 256 + n];
        else if (n < 512) v = lw2[k * 256 + (n - 256)];
        else              v = (k < 128) ? ew2[k * 128 + (n - 512)] : 0.0f;
        w2T[i] = f2bf(v);
    }
    for (int i = tid; i < 640; i += nth)
        b2[i] = (i < 256) ? hb2[i] : ((i < 512) ? lb2[i - 256] : eb2[i - 512]);
    for (int i = tid; i < 640 * 640; i += nth) {           // gwT/pwT[n*640+k] = w[k*640+n], w is (640,640)
        int n = i / 640, k = i - n * 640;
        gwT[i] = f2bf(gw[(size_t)k * 640 + n]);
        pwT[i] = f2bf(pw[(size_t)k * 640 + n]);
    }
    for (int i = tid; i < 512 * 640; i += nth) {           // owT[n*640+k] = ow[k*512+n], ow is (640,512)!
        int n = i / 640, k = i - n * 640;
        owT[i] = f2bf(ow[(size_t)k * 512 + n]);
    }
}

// ---------------------------------------------------------------- stage 1: u = silu(x @ W1 + b1), bf16
__global__ void k_u(const float* __restrict__ x,
                    const float* __restrict__ hw1, const float* __restrict__ hb1,
                    const float* __restrict__ lw1, const float* __restrict__ lb1,
                    const float* __restrict__ ew1, const float* __restrict__ eb1,
                    unsigned short* __restrict__ u)
{
    int idx = blockIdx.x * 256 + threadIdx.x;              // exact grid: BT*640/256
    int t = idx / 640, o = idx - t * 640;
    const float* xr = x + (size_t)t * CIN;
    float acc;
    if (o < 256) {
        acc = hb1[o];
        #pragma unroll
        for (int k = 0; k < 14; k++) acc += xr[k] * hw1[k * 256 + o];
    } else if (o < 512) {
        int ol = o - 256; acc = lb1[ol];
        #pragma unroll
        for (int k = 0; k < 22; k++) acc += xr[14 + k] * lw1[k * 256 + ol];
    } else {
        int ol = o - 512; acc = eb1[ol];
        #pragma unroll
        for (int k = 0; k < 8; k++) acc += xr[36 + k] * ew1[k * 128 + ol];
    }
    float s = acc / (1.0f + __expf(-acc));                 // silu
    u[idx] = f2bf(s);
}

// ---------------------------------------------------------------- stage 2: z = u @ blockdiag(W2) + b2 ; y_sum
__global__ __launch_bounds__(256) void k_z(const unsigned short* __restrict__ u,
                                           const unsigned short* __restrict__ w2T,
                                           const float* __restrict__ b2,
                                           unsigned short* __restrict__ z,
                                           float* __restrict__ y_sum)
{
    __shared__ __align__(16) unsigned short su[32 * 648]; // +8 pad: stride 648 -> 2-way (free) LDS aliasing
    int m0 = blockIdx.x * 32;
    int bidx = m0 >> 11;                                   // batch (2048 rows per batch, tile never straddles)
    const unsigned short* usrc = u + (size_t)m0 * 640;
    for (int i = threadIdx.x; i < 2560; i += 256) {        // 32*640/8 contiguous global -> padded LDS
        int e = i * 8, r = e / 640, c = e - r * 640;
        short8 v = *(const short8*)(usrc + e);
        *(short8*)&su[r * 648 + c] = v;
    }
    __syncthreads();
    int wave = threadIdx.x >> 6, lane = threadIdx.x & 63, lid = lane & 15, quad = lane >> 4;
    int r0 = (wave & 1) * 16, nh = wave >> 1;
    const f32x4 z4 = {0.f, 0.f, 0.f, 0.f};
    for (int ch = 0; ch < 5; ch++) {
        int c0 = nh * 320 + ch * 64;
        int grp = c0 >> 8;                                 // 0:h 1:l 2:e  (chunks never straddle groups)
        int abase = grp << 8;
        int Klen = (grp == 2) ? 128 : 256;
        f32x4 acc[4] = {z4, z4, z4, z4};
        for (int kk = 0; kk < Klen; kk += 32) {
            short8 a = *(const short8*)&su[(r0 + lid) * 648 + abase + kk + quad * 8];
            #pragma unroll
            for (int t = 0; t < 4; t++) {
                short8 bfr = *(const short8*)(w2T + (size_t)(c0 + t * 16 + lid) * 256 + kk + quad * 8);
                acc[t] = MFMA16(a, bfr, acc[t]);
            }
        }
        #pragma unroll
        for (int t = 0; t < 4; t++) {
            int col = c0 + t * 16 + lid;
            float bias = b2[col];
            float colsum = 0.0f;
            #pragma unroll
            for (int r = 0; r < 4; r++) {                  // D: col=lane&15, row=quad*4+r
                float zv = acc[t][r] + bias;
                z[(size_t)(m0 + r0 + quad * 4 + r) * 640 + col] = f2bf(zv);
                colsum += zv;
            }
            colsum += __shfl_xor(colsum, 16);
            colsum += __shfl_xor(colsum, 32);              // sum over this wave's 16 rows
            if (quad == 0) atomicAdd(&y_sum[bidx * 640 + col], colsum);
        }
    }
}

// ---------------------------------------------------------------- SE MLP per batch
__global__ void k_se(const float* __restrict__ y_sum, const float* __restrict__ se_w1,
                     const float* __restrict__ se_w2, float* __restrict__ se)
{
    __shared__ float ya[640];
    __shared__ float rr[160];
    int b = blockIdx.x;
    for (int i = threadIdx.x; i < 640; i += 256) ya[i] = y_sum[b * 640 + i] * (1.0f / 2048.0f);
    __syncthreads();
    for (int o = threadIdx.x; o < 160; o += 256) {
        float a = 0.f;
        for (int k = 0; k < 640; k++) a += ya[k] * se_w1[k * 160 + o];
        rr[o] = fmaxf(a, 0.f);
    }
    __syncthreads();
    for (int c = threadIdx.x; c < 640; c += 256) {
        float a = 0.f;
        for (int o = 0; o < 160; o++) a += rr[o] * se_w2[o * 640 + c];
        se[b * 640 + c] = 1.0f / (1.0f + __expf(-a));
    }
}

// ---------------------------------------------------------------- GLU: g/p GEMMs + h + LN stats
__global__ __launch_bounds__(256) void k_glu(const unsigned short* __restrict__ z,
                                             const float* __restrict__ se,
                                             const unsigned short* __restrict__ gwT,
                                             const unsigned short* __restrict__ pwT,
                                             const float* __restrict__ gb, const float* __restrict__ pb,
                                             unsigned short* __restrict__ h, float* __restrict__ hstats)
{
    __shared__ __align__(16) unsigned short sz[32 * 648];
    int m0 = blockIdx.x * 32;
    int bidx = m0 >> 11;
    const unsigned short* zsrc = z + (size_t)m0 * 640;
    const float* seb = se + bidx * 640;
    for (int i = threadIdx.x; i < 2560; i += 256) {        // stage z_se = bf16(z * se)
        int e = i * 8, r = e / 640, c = e - r * 640;
        short8 v = *(const short8*)(zsrc + e);
        unsigned short o8[8];
        #pragma unroll
        for (int j = 0; j < 8; j++) {
            float f = bf2f(((const unsigned short*)&v)[j]) * seb[c + j];
            o8[j] = f2bf(f);
        }
        *(short8*)&sz[r * 648 + c] = *(short8*)o8;
    }
    __syncthreads();
    int wave = threadIdx.x >> 6, lane = threadIdx.x & 63, lid = lane & 15, quad = lane >> 4;
    int r0 = (wave & 1) * 16, nh = wave >> 1;
    const f32x4 z4 = {0.f, 0.f, 0.f, 0.f};
    float hs[4] = {0.f, 0.f, 0.f, 0.f}, hq[4] = {0.f, 0.f, 0.f, 0.f};
    for (int ch = 0; ch < 5; ch++) {
        int c0 = nh * 320 + ch * 64;
        f32x4 ag[4] = {z4, z4, z4, z4};
        f32x4 ap[4] = {z4, z4, z4, z4};
        for (int kk = 0; kk < 640; kk += 32) {
            short8 a = *(const short8*)&sz[(r0 + lid) * 648 + kk + quad * 8];
            #pragma unroll
            for (int t = 0; t < 4; t++) {
                size_t boff = (size_t)(c0 + t * 16 + lid) * 640 + kk + quad * 8;
                short8 bg = *(const short8*)(gwT + boff);
                ag[t] = MFMA16(a, bg, ag[t]);
                short8 bp = *(const short8*)(pwT + boff);
                ap[t] = MFMA16(a, bp, ap[t]);
            }
        }
        #pragma unroll
        for (int t = 0; t < 4; t++) {
            int col = c0 + t * 16 + lid;
            float gbv = gb[col], pbv = pb[col];
            #pragma unroll
            for (int r = 0; r < 4; r++) {
                int row = r0 + quad * 4 + r;
                float gl = ag[t][r] + gbv;
                float pl = ap[t][r] + pbv;
                float sg = 1.0f / (1.0f + __expf(-gl));
                float zv = bf2f(sz[row * 648 + col]);
                float hv = sg * pl + (1.0f - sg) * zv;
                h[(size_t)(m0 + row) * 640 + col] = f2bf(hv);
                hs[r] += hv; hq[r] += hv * hv;
            }
        }
    }
    #pragma unroll
    for (int s = 1; s < 16; s <<= 1) {                     // reduce over the 16 lanes sharing rows
        #pragma unroll
        for (int r = 0; r < 4; r++) { hs[r] += __shfl_xor(hs[r], s); hq[r] += __shfl_xor(hq[r], s); }
    }
    if (lid == 0) {
        #pragma unroll
        for (int r = 0; r < 4; r++) {
            int row = m0 + r0 + quad * 4 + r;
            atomicAdd(&hstats[row * 2 + 0], hs[r]);
            atomicAdd(&hstats[row * 2 + 1], hq[r]);
        }
    }
}

// ---------------------------------------------------------------- LN + out-proj GEMM + GN stats
__global__ __launch_bounds__(256) void k_out(const unsigned short* __restrict__ h,
                                             const float* __restrict__ hstats,
                                             const float* __restrict__ ln_w, const float* __restrict__ ln_b,
                                             const unsigned short* __restrict__ owT,
                                             const float* __restrict__ ob,
                                             float* __restrict__ outp, float* __restrict__ gnstats)
{
    __shared__ __align__(16) unsigned short sh[32 * 648];
    __shared__ float sA[32], sB[32];
    int m0 = blockIdx.x * 32;
    int bidx = m0 >> 11;
    if (threadIdx.x < 32) {
        float s1 = hstats[(m0 + threadIdx.x) * 2 + 0];
        float s2 = hstats[(m0 + threadIdx.x) * 2 + 1];
        float mu = s1 * (1.0f / 640.0f);
        float var = s2 * (1.0f / 640.0f) - mu * mu;
        float rs = rsqrtf(var + EPSV);
        sA[threadIdx.x] = rs;
        sB[threadIdx.x] = -mu * rs;
    }
    __syncthreads();
    const unsigned short* hsrc = h + (size_t)m0 * 640;
    for (int i = threadIdx.x; i < 2560; i += 256) {        // stage h_ln = bf16(LN(h))
        int e = i * 8, r = e / 640, c = e - r * 640;
        short8 v = *(const short8*)(hsrc + e);
        float a = sA[r], bb = sB[r];
        unsigned short o8[8];
        #pragma unroll
        for (int j = 0; j < 8; j++) {
            float f = bf2f(((const unsigned short*)&v)[j]);
            f = f * a + bb;
            f = f * ln_w[c + j] + ln_b[c + j];
            o8[j] = f2bf(f);
        }
        *(short8*)&sh[r * 648 + c] = *(short8*)o8;
    }
    __syncthreads();
    int wave = threadIdx.x >> 6, lane = threadIdx.x & 63, lid = lane & 15, quad = lane >> 4;
    int r0 = (wave & 1) * 16, nh = wave >> 1;
    const f32x4 z4 = {0.f, 0.f, 0.f, 0.f};
    for (int ch = 0; ch < 4; ch++) {
        int c0 = nh * 256 + ch * 64;                       // one 64-wide chunk == one GN group
        f32x4 acc[4] = {z4, z4, z4, z4};
        for (int kk = 0; kk < 640; kk += 32) {
            short8 a = *(const short8*)&sh[(r0 + lid) * 648 + kk + quad * 8];
            #pragma unroll
            for (int t = 0; t < 4; t++) {
                short8 bo = *(const short8*)(owT + (size_t)(c0 + t * 16 + lid) * 640 + kk + quad * 8);
                acc[t] = MFMA16(a, bo, acc[t]);
            }
        }
        float gs = 0.f, gq = 0.f;
        #pragma unroll
        for (int t = 0; t < 4; t++) {
            int col = c0 + t * 16 + lid;
            float obv = ob[col];
            #pragma unroll
            for (int r = 0; r < 4; r++) {
                int row = r0 + quad * 4 + r;
                float v = acc[t][r] + obv;
                outp[(size_t)(m0 + row) * 512 + col] = v;
                gs += v; gq += v * v;
            }
        }
        #pragma unroll
        for (int s = 1; s < 64; s <<= 1) { gs += __shfl_xor(gs, s); gq += __shfl_xor(gq, s); }
        if (lane == 0) {
            int grp = c0 >> 6;
            atomicAdd(&gnstats[(bidx * 8 + grp) * 2 + 0], gs);
            atomicAdd(&gnstats[(bidx * 8 + grp) * 2 + 1], gq);
        }
    }
}

// ---------------------------------------------------------------- GroupNorm finalize (in-place on d_out)
__global__ void k_gn(float* __restrict__ outp, const float* __restrict__ gnstats,
                     const float* __restrict__ gn_w, const float* __restrict__ gn_b)
{
    int idx = blockIdx.x * 256 + threadIdx.x;              // one float4 per thread, exact grid
    size_t e = (size_t)idx * 4;
    int c = (int)(e & 511);
    size_t row = e >> 9;
    int b = (int)(row >> 11);
    int grp = c >> 6;
    float s1 = gnstats[(b * 8 + grp) * 2 + 0];
    float s2 = gnstats[(b * 8 + grp) * 2 + 1];
    const float inv = 1.0f / 131072.0f;                    // T_ * 64 channels per group
    float mu = s1 * inv;
    float var = s2 * inv - mu * mu;
    float rs = rsqrtf(var + EPSV);
    float4 v = *(const float4*)(outp + e);
    float4 w = *(const float4*)(gn_w + c);
    float4 bb = *(const float4*)(gn_b + c);
    float4 o;
    o.x = (v.x - mu) * rs * w.x + bb.x;
    o.y = (v.y - mu) * rs * w.y + bb.y;
    o.z = (v.z - mu) * rs * w.z + bb.z;
    o.w = (v.w - mu) * rs * w.w + bb.w;
    *(float4*)(outp + e) = o;
}

// ----------------------------------------------------------------
extern "C" void kernel_launch(void* const* d_in, const int* in_sizes, int n_in,
                              void* d_out, int out_size, void* d_ws, size_t ws_size,
                              hipStream_t stream)
{
    const float* x     = (const float*)d_in[0];
    const float* hw1   = (const float*)d_in[1];
    const float* hb1   = (const float*)d_in[2];
    const float* hw2   = (const float*)d_in[3];
    const float* hb2   = (const float*)d_in[4];
    const float* lw1   = (const float*)d_in[5];
    const float* lb1   = (const float*)d_in[6];
    const float* lw2   = (const float*)d_in[7];
    const float* lb2   = (const float*)d_in[8];
    const float* ew1   = (const float*)d_in[9];
    const float* eb1   = (const float*)d_in[10];
    const float* ew2   = (const float*)d_in[11];
    const float* eb2   = (const float*)d_in[12];
    const float* se_w1 = (const float*)d_in[13];
    const float* se_w2 = (const float*)d_in[14];
    const float* gw    = (const float*)d_in[15];
    const float* gb    = (const float*)d_in[16];
    const float* pw    = (const float*)d_in[17];
    const float* pb    = (const float*)d_in[18];
    const float* ln_w  = (const float*)d_in[19];
    const float* ln_b  = (const float*)d_in[20];
    const float* ow    = (const float*)d_in[21];
    const float* ob    = (const float*)d_in[22];
    const float* gn_w  = (const float*)d_in[23];
    const float* gn_b  = (const float*)d_in[24];

    // ---- workspace layout (small buffers first, one big 160MB staging buffer last; total ~172MB)
    char* ws = (char*)d_ws;
    size_t off = 0;
    unsigned short* w2T  = (unsigned short*)(ws + off); off += (size_t)640 * 256 * 2;
    float*          b2   = (float*)(ws + off);          off += 640 * 4;
    unsigned short* gwT  = (unsigned short*)(ws + off); off += (size_t)640 * 640 * 2;
    unsigned short* pwT  = (unsigned short*)(ws + off); off += (size_t)640 * 640 * 2;
    unsigned short* owT  = (unsigned short*)(ws + off); off += (size_t)512 * 640 * 2;
    float*          ysum = (float*)(ws + off);          off += (size_t)64 * 640 * 4;
    float*          sebuf= (float*)(ws + off);          off += (size_t)64 * 640 * 4;
    float*          hstat= (float*)(ws + off);          off += (size_t)BT * 2 * 4;
    float*          gnst = (float*)(ws + off);          off += (size_t)64 * 8 * 2 * 4;
    unsigned short* uhbuf= (unsigned short*)(ws + off); off += (size_t)BT * 640 * 2;  // u, then h

    // d_out (BT*512 fp32 = 256MB) triple-duty, strictly sequential:
    //   k_z writes z (bf16, 160MB) -> k_glu reads z / writes h(ws) -> k_out writes outp (fp32) -> k_gn in-place
    unsigned short* zbuf = (unsigned short*)d_out;
    float*          outp = (float*)d_out;

    hipMemsetAsync(ysum, 0, (size_t)64 * 640 * 4, stream);
    hipMemsetAsync(hstat, 0, (size_t)BT * 2 * 4, stream);
    hipMemsetAsync(gnst, 0, (size_t)64 * 8 * 2 * 4, stream);

    kprep<<<512, 256, 0, stream>>>(hw2, lw2, ew2, hb2, lb2, eb2, gw, pw, ow, w2T, b2, gwT, pwT, owT);
    k_u<<<(BT * 640) / 256, 256, 0, stream>>>(x, hw1, hb1, lw1, lb1, ew1, eb1, uhbuf);
    k_z<<<BT / 32, 256, 0, stream>>>(uhbuf, w2T, b2, zbuf, ysum);
    k_se<<<64, 256, 0, stream>>>(ysum, se_w1, se_w2, sebuf);
    k_glu<<<BT / 32, 256, 0, stream>>>(zbuf, sebuf, gwT, pwT, gb, pb, uhbuf, hstat);
    k_out<<<BT / 32, 256, 0, stream>>>(uhbuf, hstat, ln_w, ln_b, owT, ob, outp, gnst);
    k_gn<<<(BT * 512) / (256 * 4), 256, 0, stream>>>(outp, gnst, gn_w, gn_b);
}

// Round 3
// 2984.543 us; speedup vs baseline: 1.0847x; 1.0847x over previous
//
#include <hip/hip_runtime.h>
#include <hip/hip_bf16.h>
#include <cstdint>

// Problem constants
#define B_   64
#define T_   2048
#define CIN  44
#define D_   512
#define DCC  640
#define REDD 160
#define BT   131072        // B_*T_
#define EPSV 1e-5f

typedef __attribute__((ext_vector_type(8))) short short8;
typedef __attribute__((ext_vector_type(4))) float f32x4;

#define MFMA16(a,b,c) __builtin_amdgcn_mfma_f32_16x16x32_bf16(a,b,c,0,0,0)

__device__ __forceinline__ float bf2f(unsigned short u) {
    union { unsigned int i; float f; } v; v.i = ((unsigned int)u) << 16; return v.f;
}
__device__ __forceinline__ unsigned short f2bf(float f) {
    union { float f; unsigned int i; } v; v.f = f;
    unsigned int r = v.i + 0x7FFFu + ((v.i >> 16) & 1u);   // RNE
    return (unsigned short)(r >> 16);
}

// ---------------------------------------------------------------- prep: weights -> bf16 FRAGMENT-PACKED
// Packed layout: for chunk c (64 cols), K-slab kb (32 k), tile t (16 cols):
//   packed[ ((c*(K/32) + kb)*4 + t)*512 + lane*8 + j ]  = W^T[n][k]
// with lane = quad*16+lid, n = c*64 + t*16 + lid, k = kb*32 + quad*8 + j.
// A wave's B-fragment load is then ONE contiguous 1KB coalesced dwordx4.
__global__ void kprep(const float* __restrict__ hw2, const float* __restrict__ lw2, const float* __restrict__ ew2,
                      const float* __restrict__ hb2, const float* __restrict__ lb2, const float* __restrict__ eb2,
                      const float* __restrict__ gw,  const float* __restrict__ pw,  const float* __restrict__ ow,
                      unsigned short* __restrict__ w2T, float* __restrict__ b2,
                      unsigned short* __restrict__ gwT, unsigned short* __restrict__ pwT,
                      unsigned short* __restrict__ owT)
{
    int tid = blockIdx.x * blockDim.x + threadIdx.x;
    int nth = gridDim.x * blockDim.x;
    // gwT/pwT: N=640, K=640 -> chunk size 20*2048 = 40960
    for (int i = tid; i < 640 * 640; i += nth) {
        int c  = i / 40960, r = i - c * 40960;
        int kb = r / 2048;  int r2 = r - kb * 2048;
        int t  = r2 >> 9;   int l8 = r2 & 511;
        int lane = l8 >> 3, j = l8 & 7;
        int lid = lane & 15, quad = lane >> 4;
        int n = c * 64 + t * 16 + lid;
        int k = kb * 32 + quad * 8 + j;
        gwT[i] = f2bf(gw[(size_t)k * 640 + n]);
        pwT[i] = f2bf(pw[(size_t)k * 640 + n]);
    }
    // owT: N=512, K=640 (ow stride 512!)
    for (int i = tid; i < 512 * 640; i += nth) {
        int c  = i / 40960, r = i - c * 40960;
        int kb = r / 2048;  int r2 = r - kb * 2048;
        int t  = r2 >> 9;   int l8 = r2 & 511;
        int lane = l8 >> 3, j = l8 & 7;
        int lid = lane & 15, quad = lane >> 4;
        int n = c * 64 + t * 16 + lid;
        int k = kb * 32 + quad * 8 + j;
        owT[i] = f2bf(ow[(size_t)k * 512 + n]);
    }
    // w2T: N=640, K=256 local -> chunk size 8*2048 = 16384; block-diag groups
    for (int i = tid; i < 640 * 256; i += nth) {
        int c  = i / 16384, r = i - c * 16384;
        int kb = r / 2048;  int r2 = r - kb * 2048;
        int t  = r2 >> 9;   int l8 = r2 & 511;
        int lane = l8 >> 3, j = l8 & 7;
        int lid = lane & 15, quad = lane >> 4;
        int n = c * 64 + t * 16 + lid;
        int k = kb * 32 + quad * 8 + j;   // local k within group
        float v;
        if (n < 256)      v = hw2[k * 256 + n];
        else if (n < 512) v = lw2[k * 256 + (n - 256)];
        else              v = (k < 128) ? ew2[k * 128 + (n - 512)] : 0.0f;
        w2T[i] = f2bf(v);
    }
    for (int i = tid; i < 640; i += nth)
        b2[i] = (i < 256) ? hb2[i] : ((i < 512) ? lb2[i - 256] : eb2[i - 512]);
}

// ---------------------------------------------------------------- stage 1: u = silu(x @ W1 + b1), bf16
__global__ void k_u(const float* __restrict__ x,
                    const float* __restrict__ hw1, const float* __restrict__ hb1,
                    const float* __restrict__ lw1, const float* __restrict__ lb1,
                    const float* __restrict__ ew1, const float* __restrict__ eb1,
                    unsigned short* __restrict__ u)
{
    int idx = blockIdx.x * 256 + threadIdx.x;              // exact grid: BT*640/256
    int t = idx / 640, o = idx - t * 640;
    const float* xr = x + (size_t)t * CIN;
    float acc;
    if (o < 256) {
        acc = hb1[o];
        #pragma unroll
        for (int k = 0; k < 14; k++) acc += xr[k] * hw1[k * 256 + o];
    } else if (o < 512) {
        int ol = o - 256; acc = lb1[ol];
        #pragma unroll
        for (int k = 0; k < 22; k++) acc += xr[14 + k] * lw1[k * 256 + ol];
    } else {
        int ol = o - 512; acc = eb1[ol];
        #pragma unroll
        for (int k = 0; k < 8; k++) acc += xr[36 + k] * ew1[k * 128 + ol];
    }
    float s = acc / (1.0f + __expf(-acc));                 // silu
    u[idx] = f2bf(s);
}

// ---------------------------------------------------------------- stage 2: z = u @ blockdiag(W2) + b2 ; y_sum
__global__ __launch_bounds__(256) void k_z(const unsigned short* __restrict__ u,
                                           const unsigned short* __restrict__ w2T,
                                           const float* __restrict__ b2,
                                           unsigned short* __restrict__ z,
                                           float* __restrict__ y_sum)
{
    __shared__ __align__(16) unsigned short su[32 * 648];
    int m0 = blockIdx.x * 32;
    int bidx = m0 >> 11;
    const unsigned short* usrc = u + (size_t)m0 * 640;
    for (int i = threadIdx.x; i < 2560; i += 256) {
        int e = i * 8, r = e / 640, c = e - r * 640;
        short8 v = *(const short8*)(usrc + e);
        *(short8*)&su[r * 648 + c] = v;
    }
    __syncthreads();
    int wave = threadIdx.x >> 6, lane = threadIdx.x & 63, lid = lane & 15, quad = lane >> 4;
    int r0 = (wave & 1) * 16, nh = wave >> 1;
    const f32x4 z4 = {0.f, 0.f, 0.f, 0.f};
    for (int ch = 0; ch < 5; ch++) {
        int c0 = nh * 320 + ch * 64;
        int grp = c0 >> 8;
        int abase = grp << 8;
        int Klen = (grp == 2) ? 128 : 256;
        f32x4 acc[4] = {z4, z4, z4, z4};
        for (int kk = 0; kk < Klen; kk += 32) {
            short8 a = *(const short8*)&su[(r0 + lid) * 648 + abase + kk + quad * 8];
            const unsigned short* bb = w2T + (size_t)((c0 >> 6) * 8 + (kk >> 5)) * 2048 + lane * 8;
            #pragma unroll
            for (int t = 0; t < 4; t++) {
                short8 bfr = *(const short8*)(bb + t * 512);
                acc[t] = MFMA16(a, bfr, acc[t]);
            }
        }
        #pragma unroll
        for (int t = 0; t < 4; t++) {
            int col = c0 + t * 16 + lid;
            float bias = b2[col];
            float colsum = 0.0f;
            #pragma unroll
            for (int r = 0; r < 4; r++) {
                float zv = acc[t][r] + bias;
                z[(size_t)(m0 + r0 + quad * 4 + r) * 640 + col] = f2bf(zv);
                colsum += zv;
            }
            colsum += __shfl_xor(colsum, 16);
            colsum += __shfl_xor(colsum, 32);
            if (quad == 0) atomicAdd(&y_sum[bidx * 640 + col], colsum);
        }
    }
}

// ---------------------------------------------------------------- SE MLP per batch
__global__ void k_se(const float* __restrict__ y_sum, const float* __restrict__ se_w1,
                     const float* __restrict__ se_w2, float* __restrict__ se)
{
    __shared__ float ya[640];
    __shared__ float rr[160];
    int b = blockIdx.x;
    for (int i = threadIdx.x; i < 640; i += 256) ya[i] = y_sum[b * 640 + i] * (1.0f / 2048.0f);
    __syncthreads();
    for (int o = threadIdx.x; o < 160; o += 256) {
        float a = 0.f;
        for (int k = 0; k < 640; k++) a += ya[k] * se_w1[k * 160 + o];
        rr[o] = fmaxf(a, 0.f);
    }
    __syncthreads();
    for (int c = threadIdx.x; c < 640; c += 256) {
        float a = 0.f;
        for (int o = 0; o < 160; o++) a += rr[o] * se_w2[o * 640 + c];
        se[b * 640 + c] = 1.0f / (1.0f + __expf(-a));
    }
}

// ---------------------------------------------------------------- GLU: g/p GEMMs + h + LN stats
__global__ __launch_bounds__(256) void k_glu(const unsigned short* __restrict__ z,
                                             const float* __restrict__ se,
                                             const unsigned short* __restrict__ gwT,
                                             const unsigned short* __restrict__ pwT,
                                             const float* __restrict__ gb, const float* __restrict__ pb,
                                             unsigned short* __restrict__ h, float* __restrict__ hstats)
{
    __shared__ __align__(16) unsigned short sz[32 * 648];
    int m0 = blockIdx.x * 32;
    int bidx = m0 >> 11;
    const unsigned short* zsrc = z + (size_t)m0 * 640;
    const float* seb = se + bidx * 640;
    for (int i = threadIdx.x; i < 2560; i += 256) {        // stage z_se = bf16(z * se)
        int e = i * 8, r = e / 640, c = e - r * 640;
        short8 v = *(const short8*)(zsrc + e);
        unsigned short o8[8];
        #pragma unroll
        for (int j = 0; j < 8; j++) {
            float f = bf2f(((const unsigned short*)&v)[j]) * seb[c + j];
            o8[j] = f2bf(f);
        }
        *(short8*)&sz[r * 648 + c] = *(short8*)o8;
    }
    __syncthreads();
    int wave = threadIdx.x >> 6, lane = threadIdx.x & 63, lid = lane & 15, quad = lane >> 4;
    int r0 = (wave & 1) * 16, nh = wave >> 1;
    const f32x4 z4 = {0.f, 0.f, 0.f, 0.f};
    float hs[4] = {0.f, 0.f, 0.f, 0.f}, hq[4] = {0.f, 0.f, 0.f, 0.f};
    for (int ch = 0; ch < 5; ch++) {
        int c0 = nh * 320 + ch * 64;
        f32x4 ag[4] = {z4, z4, z4, z4};
        f32x4 ap[4] = {z4, z4, z4, z4};
        for (int kk = 0; kk < 640; kk += 32) {
            short8 a = *(const short8*)&sz[(r0 + lid) * 648 + kk + quad * 8];
            size_t bbase = (size_t)((c0 >> 6) * 20 + (kk >> 5)) * 2048 + lane * 8;
            const unsigned short* bg = gwT + bbase;
            const unsigned short* bp = pwT + bbase;
            #pragma unroll
            for (int t = 0; t < 4; t++) {
                short8 vg = *(const short8*)(bg + t * 512);
                ag[t] = MFMA16(a, vg, ag[t]);
                short8 vp = *(const short8*)(bp + t * 512);
                ap[t] = MFMA16(a, vp, ap[t]);
            }
        }
        #pragma unroll
        for (int t = 0; t < 4; t++) {
            int col = c0 + t * 16 + lid;
            float gbv = gb[col], pbv = pb[col];
            #pragma unroll
            for (int r = 0; r < 4; r++) {
                int row = r0 + quad * 4 + r;
                float gl = ag[t][r] + gbv;
                float pl = ap[t][r] + pbv;
                float sg = 1.0f / (1.0f + __expf(-gl));
                float zv = bf2f(sz[row * 648 + col]);
                float hv = sg * pl + (1.0f - sg) * zv;
                h[(size_t)(m0 + row) * 640 + col] = f2bf(hv);
                hs[r] += hv; hq[r] += hv * hv;
            }
        }
    }
    #pragma unroll
    for (int s = 1; s < 16; s <<= 1) {
        #pragma unroll
        for (int r = 0; r < 4; r++) { hs[r] += __shfl_xor(hs[r], s); hq[r] += __shfl_xor(hq[r], s); }
    }
    if (lid == 0) {
        #pragma unroll
        for (int r = 0; r < 4; r++) {
            int row = m0 + r0 + quad * 4 + r;
            atomicAdd(&hstats[row * 2 + 0], hs[r]);
            atomicAdd(&hstats[row * 2 + 1], hq[r]);
        }
    }
}

// ---------------------------------------------------------------- LN + out-proj GEMM + GN stats
__global__ __launch_bounds__(256) void k_out(const unsigned short* __restrict__ h,
                                             const float* __restrict__ hstats,
                                             const float* __restrict__ ln_w, const float* __restrict__ ln_b,
                                             const unsigned short* __restrict__ owT,
                                             const float* __restrict__ ob,
                                             float* __restrict__ outp, float* __restrict__ gnstats)
{
    __shared__ __align__(16) unsigned short sh[32 * 648];
    __shared__ float sA[32], sB[32];
    int m0 = blockIdx.x * 32;
    int bidx = m0 >> 11;
    if (threadIdx.x < 32) {
        float s1 = hstats[(m0 + threadIdx.x) * 2 + 0];
        float s2 = hstats[(m0 + threadIdx.x) * 2 + 1];
        float mu = s1 * (1.0f / 640.0f);
        float var = s2 * (1.0f / 640.0f) - mu * mu;
        float rs = rsqrtf(var + EPSV);
        sA[threadIdx.x] = rs;
        sB[threadIdx.x] = -mu * rs;
    }
    __syncthreads();
    const unsigned short* hsrc = h + (size_t)m0 * 640;
    for (int i = threadIdx.x; i < 2560; i += 256) {        // stage h_ln = bf16(LN(h))
        int e = i * 8, r = e / 640, c = e - r * 640;
        short8 v = *(const short8*)(hsrc + e);
        float a = sA[r], bb = sB[r];
        unsigned short o8[8];
        #pragma unroll
        for (int j = 0; j < 8; j++) {
            float f = bf2f(((const unsigned short*)&v)[j]);
            f = f * a + bb;
            f = f * ln_w[c + j] + ln_b[c + j];
            o8[j] = f2bf(f);
        }
        *(short8*)&sh[r * 648 + c] = *(short8*)o8;
    }
    __syncthreads();
    int wave = threadIdx.x >> 6, lane = threadIdx.x & 63, lid = lane & 15, quad = lane >> 4;
    int r0 = (wave & 1) * 16, nh = wave >> 1;
    const f32x4 z4 = {0.f, 0.f, 0.f, 0.f};
    for (int ch = 0; ch < 4; ch++) {
        int c0 = nh * 256 + ch * 64;                       // one 64-wide chunk == one GN group
        f32x4 acc[4] = {z4, z4, z4, z4};
        for (int kk = 0; kk < 640; kk += 32) {
            short8 a = *(const short8*)&sh[(r0 + lid) * 648 + kk + quad * 8];
            const unsigned short* bb = owT + (size_t)((c0 >> 6) * 20 + (kk >> 5)) * 2048 + lane * 8;
            #pragma unroll
            for (int t = 0; t < 4; t++) {
                short8 bo = *(const short8*)(bb + t * 512);
                acc[t] = MFMA16(a, bo, acc[t]);
            }
        }
        float gs = 0.f, gq = 0.f;
        #pragma unroll
        for (int t = 0; t < 4; t++) {
            int col = c0 + t * 16 + lid;
            float obv = ob[col];
            #pragma unroll
            for (int r = 0; r < 4; r++) {
                int row = r0 + quad * 4 + r;
                float v = acc[t][r] + obv;
                outp[(size_t)(m0 + row) * 512 + col] = v;
                gs += v; gq += v * v;
            }
        }
        #pragma unroll
        for (int s = 1; s < 64; s <<= 1) { gs += __shfl_xor(gs, s); gq += __shfl_xor(gq, s); }
        if (lane == 0) {
            int grp = c0 >> 6;
            atomicAdd(&gnstats[(bidx * 8 + grp) * 2 + 0], gs);
            atomicAdd(&gnstats[(bidx * 8 + grp) * 2 + 1], gq);
        }
    }
}

// ---------------------------------------------------------------- GroupNorm finalize (in-place on d_out)
__global__ void k_gn(float* __restrict__ outp, const float* __restrict__ gnstats,
                     const float* __restrict__ gn_w, const float* __restrict__ gn_b)
{
    int idx = blockIdx.x * 256 + threadIdx.x;
    size_t e = (size_t)idx * 4;
    int c = (int)(e & 511);
    size_t row = e >> 9;
    int b = (int)(row >> 11);
    int grp = c >> 6;
    float s1 = gnstats[(b * 8 + grp) * 2 + 0];
    float s2 = gnstats[(b * 8 + grp) * 2 + 1];
    const float inv = 1.0f / 131072.0f;
    float mu = s1 * inv;
    float var = s2 * inv - mu * mu;
    float rs = rsqrtf(var + EPSV);
    float4 v = *(const float4*)(outp + e);
    float4 w = *(const float4*)(gn_w + c);
    float4 bb = *(const float4*)(gn_b + c);
    float4 o;
    o.x = (v.x - mu) * rs * w.x + bb.x;
    o.y = (v.y - mu) * rs * w.y + bb.y;
    o.z = (v.z - mu) * rs * w.z + bb.z;
    o.w = (v.w - mu) * rs * w.w + bb.w;
    *(float4*)(outp + e) = o;
}

// ----------------------------------------------------------------
extern "C" void kernel_launch(void* const* d_in, const int* in_sizes, int n_in,
                              void* d_out, int out_size, void* d_ws, size_t ws_size,
                              hipStream_t stream)
{
    const float* x     = (const float*)d_in[0];
    const float* hw1   = (const float*)d_in[1];
    const float* hb1   = (const float*)d_in[2];
    const float* hw2   = (const float*)d_in[3];
    const float* hb2   = (const float*)d_in[4];
    const float* lw1   = (const float*)d_in[5];
    const float* lb1   = (const float*)d_in[6];
    const float* lw2   = (const float*)d_in[7];
    const float* lb2   = (const float*)d_in[8];
    const float* ew1   = (const float*)d_in[9];
    const float* eb1   = (const float*)d_in[10];
    const float* ew2   = (const float*)d_in[11];
    const float* eb2   = (const float*)d_in[12];
    const float* se_w1 = (const float*)d_in[13];
    const float* se_w2 = (const float*)d_in[14];
    const float* gw    = (const float*)d_in[15];
    const float* gb    = (const float*)d_in[16];
    const float* pw    = (const float*)d_in[17];
    const float* pb    = (const float*)d_in[18];
    const float* ln_w  = (const float*)d_in[19];
    const float* ln_b  = (const float*)d_in[20];
    const float* ow    = (const float*)d_in[21];
    const float* ob    = (const float*)d_in[22];
    const float* gn_w  = (const float*)d_in[23];
    const float* gn_b  = (const float*)d_in[24];

    char* ws = (char*)d_ws;
    size_t off = 0;
    unsigned short* w2T  = (unsigned short*)(ws + off); off += (size_t)640 * 256 * 2;
    float*          b2   = (float*)(ws + off);          off += 640 * 4;
    unsigned short* gwT  = (unsigned short*)(ws + off); off += (size_t)640 * 640 * 2;
    unsigned short* pwT  = (unsigned short*)(ws + off); off += (size_t)640 * 640 * 2;
    unsigned short* owT  = (unsigned short*)(ws + off); off += (size_t)512 * 640 * 2;
    float*          ysum = (float*)(ws + off);          off += (size_t)64 * 640 * 4;
    float*          sebuf= (float*)(ws + off);          off += (size_t)64 * 640 * 4;
    float*          hstat= (float*)(ws + off);          off += (size_t)BT * 2 * 4;
    float*          gnst = (float*)(ws + off);          off += (size_t)64 * 8 * 2 * 4;
    unsigned short* uhbuf= (unsigned short*)(ws + off); off += (size_t)BT * 640 * 2;  // u, then h

    unsigned short* zbuf = (unsigned short*)d_out;
    float*          outp = (float*)d_out;

    hipMemsetAsync(ysum, 0, (size_t)64 * 640 * 4, stream);
    hipMemsetAsync(hstat, 0, (size_t)BT * 2 * 4, stream);
    hipMemsetAsync(gnst, 0, (size_t)64 * 8 * 2 * 4, stream);

    kprep<<<512, 256, 0, stream>>>(hw2, lw2, ew2, hb2, lb2, eb2, gw, pw, ow, w2T, b2, gwT, pwT, owT);
    k_u<<<(BT * 640) / 256, 256, 0, stream>>>(x, hw1, hb1, lw1, lb1, ew1, eb1, uhbuf);
    k_z<<<BT / 32, 256, 0, stream>>>(uhbuf, w2T, b2, zbuf, ysum);
    k_se<<<64, 256, 0, stream>>>(ysum, se_w1, se_w2, sebuf);
    k_glu<<<BT / 32, 256, 0, stream>>>(zbuf, sebuf, gwT, pwT, gb, pb, uhbuf, hstat);
    k_out<<<BT / 32, 256, 0, stream>>>(uhbuf, hstat, ln_w, ln_b, owT, ob, outp, gnst);
    k_gn<<<(BT * 512) / (256 * 4), 256, 0, stream>>>(outp, gnst, gn_w, gn_b);
}